// Round 12
// baseline (18936.725 us; speedup 1.0000x reference)
//
#include <hip/hip_runtime.h>

#define SEQL 512
#define BATCH 256
#define EMB 256
#define HID 512
#define NTOT 2048  // 4*HID

typedef __attribute__((ext_vector_type(8))) short bf16x8;
typedef __attribute__((ext_vector_type(4))) float f32x4;
typedef __attribute__((ext_vector_type(4))) unsigned u32x4;
typedef __attribute__((ext_vector_type(4))) unsigned short us4;
typedef unsigned short u16;
typedef unsigned u32;

// ---------- helpers ----------
static __device__ __forceinline__ u16 f2bf(float f) {
  unsigned u = __float_as_uint(f);
  u += 0x7FFFu + ((u >> 16) & 1u);  // RNE
  return (u16)(u >> 16);
}
static __device__ __forceinline__ float bf2f(u16 s) {
  return __uint_as_float(((unsigned)s) << 16);
}
static __device__ __forceinline__ float sigmoidf_(float z) {
  return 1.f / (1.f + __expf(-z));
}
static __device__ __forceinline__ float tanhf_(float x) {
  float e = __expf(2.f * fabsf(x));
  float t = 1.f - 2.f / (e + 1.f);
  return copysignf(t, x);
}
static __device__ __forceinline__ f32x4 mfma16(bf16x8 a, bf16x8 b, f32x4 c) {
  return __builtin_amdgcn_mfma_f32_16x16x32_bf16(a, b, c, 0, 0, 0);
}
static __device__ __forceinline__ void gld16(const u16* g, u16* l) {
  __builtin_amdgcn_global_load_lds((const __attribute__((address_space(1))) void*)g,
                                   (__attribute__((address_space(3))) void*)l, 16, 0, 0);
}

// ---------- split f32 -> bf16 hi/lo (R3 verbatim) ----------
__global__ void k_split(const float* __restrict__ src, u16* __restrict__ hi,
                        u16* __restrict__ lo, int n) {
  for (int i = blockIdx.x * blockDim.x + threadIdx.x; i < n;
       i += gridDim.x * blockDim.x) {
    float v = src[i];
    u16 h = f2bf(v);
    hi[i] = h;
    lo[i] = f2bf(v - bf2f(h));
  }
}

// bias2[n] : n = g*512+j ; 2*b for f,i,o ; 1*b for a  (R3 verbatim)
__global__ void k_bias2(const float* __restrict__ bf_, const float* __restrict__ bi_,
                        const float* __restrict__ bo_, const float* __restrict__ ba_,
                        float* __restrict__ bias2) {
  int n = blockIdx.x * blockDim.x + threadIdx.x;
  if (n >= NTOT) return;
  int g = n >> 9, j = n & 511;
  const float* p = (g == 0) ? bf_ : (g == 1) ? bi_ : (g == 2) ? bo_ : ba_;
  bias2[n] = ((g < 3) ? 2.f : 1.f) * p[j];
}

// ---------- chunk GEMM with fused X split (R5/R6/R8 VERBATIM — passed 3x) ------
// G2 layout: [tloc][bgrp 16][gate 4][j 512][b 16] f32
__global__ __launch_bounds__(256) void k_gemm(
    const float* __restrict__ X, const u16* __restrict__ Bhi,
    const u16* __restrict__ Blo, const float* __restrict__ bias2,
    float* __restrict__ G2) {
  __shared__ u16 lds[4][128 * 64];
  const int tid = threadIdx.x;
  const int lane = tid & 63;
  const int w = tid >> 6;
  const int wm = (w >> 1) * 64, wn = (w & 1) * 64;
  const int m0 = blockIdx.y * 128, n0 = blockIdx.x * 128;
  const int l15 = lane & 15, lhi = lane >> 4;

  f32x4 acc[4][4] = {};

  for (int k0 = 0; k0 < EMB; k0 += 64) {
    __syncthreads();
#pragma unroll
    for (int c = 0; c < 4; ++c) {
      int idx = tid + c * 256;
      int row = idx >> 3;
      int col = (idx & 7) * 8;
      size_t gb = (size_t)(n0 + row) * EMB + k0 + col;
      gld16(Bhi + gb, &lds[2][idx * 8]);
      gld16(Blo + gb, &lds[3][idx * 8]);
    }
#pragma unroll
    for (int c = 0; c < 8; ++c) {
      int idx = tid + c * 256;
      int row = idx >> 4;
      int c4 = (idx & 15) * 4;
      f32x4 xv = *(const f32x4*)&X[(size_t)(m0 + row) * EMB + k0 + c4];
      us4 h4, l4;
#pragma unroll
      for (int e = 0; e < 4; ++e) {
        u16 h = f2bf(xv[e]);
        h4[e] = h;
        l4[e] = f2bf(xv[e] - bf2f(h));
      }
      *(us4*)&lds[0][row * 64 + c4] = h4;
      *(us4*)&lds[1][row * 64 + c4] = l4;
    }
    __syncthreads();
#pragma unroll
    for (int ks = 0; ks < 2; ++ks) {
      int ko = ks * 32 + lhi * 8;
      bf16x8 ah[4], al[4], bh[4], bl[4];
#pragma unroll
      for (int f = 0; f < 4; ++f) {
        int ra = (wm + f * 16 + l15) * 64 + ko;
        int rb = (wn + f * 16 + l15) * 64 + ko;
        ah[f] = *(const bf16x8*)&lds[0][ra];
        al[f] = *(const bf16x8*)&lds[1][ra];
        bh[f] = *(const bf16x8*)&lds[2][rb];
        bl[f] = *(const bf16x8*)&lds[3][rb];
      }
#pragma unroll
      for (int i = 0; i < 4; ++i)
#pragma unroll
        for (int j = 0; j < 4; ++j) {
          acc[i][j] = mfma16(ah[i], bh[j], acc[i][j]);
          acc[i][j] = mfma16(ah[i], bl[j], acc[i][j]);
          acc[i][j] = mfma16(al[i], bh[j], acc[i][j]);
        }
    }
  }
#pragma unroll
  for (int j = 0; j < 4; ++j) {
    int n = n0 + wn + j * 16 + l15;
    float bv = bias2[n];
    int g = n >> 9, jj = n & 511;
#pragma unroll
    for (int i = 0; i < 4; ++i) {
      int mb = m0 + wm + i * 16 + lhi * 4;
      int tloc = mb >> 8, brow = mb & 255;
      int bgrp = brow >> 4, b15 = brow & 15;
      f32x4 v = acc[i][j];
      v[0] += bv; v[1] += bv; v[2] += bv; v[3] += bv;
      size_t addr = ((((size_t)tloc * 16 + bgrp) * 4 + g) * 512 + jj) * 16 + b15;
      *(f32x4*)&G2[addr] = v;
    }
  }
}

// ---------- recurrence v12: 16 independent blocks, LDS-only h exchange ----------
// Block bid = batch-group [bid*16, bid*16+16). 1024 threads = 16 waves.
// Wave w: j-slice [w*32, w*32+32), full K=512 (no split-K, no owners).
// Waa hi+lo fragments in VGPRs (R3-proven orientation). h in LDS double buffer,
// packed u32 (hi|lo), XOR-swizzled (T2): u32idx = b*512 + (col ^ ((b&7)<<2)).
// ONE __syncthreads per step. No global h traffic except chunk boundaries.
__global__ __launch_bounds__(1024, 1) void k_rnn2(
    const u16* __restrict__ WaaHi, const u16* __restrict__ WaaLo,
    const float* __restrict__ G2,
    u32* __restrict__ hSave, float* __restrict__ cSave,
    float* __restrict__ out, int t0, int nsteps) {
  __shared__ u32 hb[2][8192];  // 2 x 32KB, row stride 512 u32
  const int tid = threadIdx.x, lane = tid & 63, w = tid >> 6;
  const int l15 = lane & 15, lhi = lane >> 4;
  const int bid = blockIdx.x;
  const int jbase = w * 32;

  // persistent Waa B-fragments (hi+lo) in VGPRs, pinned (R3-proven pattern)
  bf16x8 BH[2][16], BL[2][16];
#pragma unroll
  for (int nf = 0; nf < 2; ++nf)
#pragma unroll
    for (int kf = 0; kf < 16; ++kf) {
      size_t base = (size_t)(jbase + nf * 16 + l15) * HID + kf * 32 + lhi * 8;
      BH[nf][kf] = *(const bf16x8*)&WaaHi[base];
      BL[nf][kf] = *(const bf16x8*)&WaaLo[base];
    }
#pragma unroll
  for (int nf = 0; nf < 2; ++nf)
#pragma unroll
    for (int kf = 0; kf < 16; ++kf) {
      asm volatile("" : "+v"(BH[nf][kf]));
      asm volatile("" : "+v"(BL[nf][kf]));
    }

  f32x4 cc[2] = {};
  const size_t cbase = ((size_t)bid * 1024 + tid) * 8;
  if (t0 > 0) {
    cc[0] = *(const f32x4*)&cSave[cbase];
    cc[1] = *(const f32x4*)&cSave[cbase + 4];
  }

  // h(t0) into hb[0]: zeros at t0==0, else restore from hSave (same block wrote it)
  if (t0 == 0) {
    for (int i = tid; i < 16384; i += 1024) ((u32*)hb)[i] = 0;
  } else {
#pragma unroll
    for (int q = 0; q < 8; ++q) {
      int idx = tid + q * 1024;  // 0..8191
      int b = idx >> 9, j = idx & 511;
      hb[0][b * 512 + (j ^ ((b & 7) << 2))] = hSave[(size_t)bid * 8192 + idx];
    }
  }
  __syncthreads();

  const int sw = (l15 & 7) << 2;   // A-frag row b = l15
  const int rrow = l15 * 512;

  for (int tl = 0; tl < nsteps; ++tl) {
    const int gt = t0 + tl;
    const u32* hr = hb[tl & 1];
    u32* hw = hb[(tl + 1) & 1];

    // gate preactivations (plain cached loads; overlap LDS+MFMA below)
    f32x4 gq[2][4];
    {
      const float* gp = G2 + ((size_t)tl * 16 + bid) * 32768;
#pragma unroll
      for (int nf = 0; nf < 2; ++nf)
#pragma unroll
        for (int g = 0; g < 4; ++g)
          gq[nf][g] = *(const f32x4*)(gp + ((size_t)g * 512 + jbase + nf * 16 + l15) * 16 + lhi * 4);
    }

    // full-K MFMA, A (h) streamed from LDS, 6 independent chains
    f32x4 p00 = {0.f, 0.f, 0.f, 0.f}, p01 = p00, p02 = p00;
    f32x4 p10 = p00, p11 = p00, p12 = p00;
#pragma unroll
    for (int kf = 0; kf < 16; ++kf) {
      int c0 = kf * 32 + lhi * 8;  // 8-aligned -> granule-safe XOR
      u32x4 q0 = *(const u32x4*)&hr[rrow + (c0 ^ sw)];
      u32x4 q1 = *(const u32x4*)&hr[rrow + ((c0 + 4) ^ sw)];
      u32x4 hv = {(q0[0] & 0xffffu) | (q0[1] << 16), (q0[2] & 0xffffu) | (q0[3] << 16),
                  (q1[0] & 0xffffu) | (q1[1] << 16), (q1[2] & 0xffffu) | (q1[3] << 16)};
      u32x4 lv = {(q0[0] >> 16) | (q0[1] & 0xffff0000u), (q0[2] >> 16) | (q0[3] & 0xffff0000u),
                  (q1[0] >> 16) | (q1[1] & 0xffff0000u), (q1[2] >> 16) | (q1[3] & 0xffff0000u)};
      bf16x8 aH = *(bf16x8*)&hv;
      bf16x8 aL = *(bf16x8*)&lv;
      p00 = mfma16(aH, BH[0][kf], p00);
      p01 = mfma16(aL, BH[0][kf], p01);
      p02 = mfma16(aH, BL[0][kf], p02);
      p10 = mfma16(aH, BH[1][kf], p10);
      p11 = mfma16(aL, BH[1][kf], p11);
      p12 = mfma16(aH, BL[1][kf], p12);
    }
    f32x4 z0 = (p00 + p01) + p02;
    f32x4 z1 = (p10 + p11) + p12;

    // gates + c/h update; h -> LDS (swizzled) or boundary buffers
#pragma unroll
    for (int nf = 0; nf < 2; ++nf) {
      f32x4 z4 = nf ? z1 : z0;
#pragma unroll
      for (int r = 0; r < 4; ++r) {
        float z = z4[r];
        float ft = sigmoidf_(gq[nf][0][r] + z);
        float it = sigmoidf_(gq[nf][1][r] + z);
        float ot = sigmoidf_(gq[nf][2][r] + z);
        float cp = tanhf_(gq[nf][3][r] + z);
        float cn = ft * cc[nf][r] + it * cp;
        cc[nf][r] = cn;
        float h = ot * tanhf_(cn);
        int b = lhi * 4 + r;
        int j = jbase + nf * 16 + l15;
        if (gt == SEQL - 1) {
          out[((size_t)bid * 16 + b) * HID + j] = h;
        } else {
          u16 hh = f2bf(h), hl = f2bf(h - bf2f(hh));
          u32 d = (u32)hh | ((u32)hl << 16);
          if (tl == nsteps - 1) hSave[(size_t)bid * 8192 + b * 512 + j] = d;
          else hw[b * 512 + (j ^ ((b & 7) << 2))] = d;
        }
      }
    }
    __syncthreads();  // h(t+1) visible; hr free for overwrite next step
  }

  if (t0 + nsteps < SEQL) {
    *(f32x4*)&cSave[cbase] = cc[0];
    *(f32x4*)&cSave[cbase + 4] = cc[1];
  }
}

// ---------- host ----------
extern "C" void kernel_launch(void* const* d_in, const int* in_sizes, int n_in,
                              void* d_out, int out_size, void* d_ws, size_t ws_size,
                              hipStream_t stream) {
  const float* X   = (const float*)d_in[0];
  const float* Wfx = (const float*)d_in[1];
  const float* Wix = (const float*)d_in[2];
  const float* Wox = (const float*)d_in[3];
  const float* Wax = (const float*)d_in[4];
  const float* Waa = (const float*)d_in[5];
  const float* bfp = (const float*)d_in[6];
  const float* bip = (const float*)d_in[7];
  const float* bop = (const float*)d_in[8];
  const float* bap = (const float*)d_in[9];
  float* out = (float*)d_out;

  char* ws = (char*)d_ws;
  size_t off = 0;
  auto take = [&](size_t n) {
    void* p = ws + off;
    off += (n + 255) & ~(size_t)255;
    return p;
  };
  u16* WxHi   = (u16*)take((size_t)NTOT * EMB * 2);   // 1MB
  u16* WxLo   = (u16*)take((size_t)NTOT * EMB * 2);   // 1MB
  u16* WaaHi  = (u16*)take((size_t)HID * HID * 2);    // 512KB
  u16* WaaLo  = (u16*)take((size_t)HID * HID * 2);    // 512KB
  float* bias2 = (float*)take((size_t)NTOT * 4);
  u32* hSave  = (u32*)take((size_t)16 * 8192 * 4);    // 512KB chunk-boundary h
  float* cSave = (float*)take((size_t)16 * 1024 * 8 * 4);  // 512KB
  size_t fixed_end = off;

  const size_t perstep = (size_t)BATCH * NTOT * 4;  // 2MB G2 per step
  int C = 0;
  const int cands[] = {512, 256, 128, 64, 32, 16, 8, 4, 2, 1};
  for (int cand : cands)
    if (fixed_end + (size_t)cand * perstep <= ws_size) { C = cand; break; }
  if (C == 0) return;
  float* G2 = (float*)take((size_t)C * perstep);

  // one-time prep
  const float* wx[4] = {Wfx, Wix, Wox, Wax};
  for (int g = 0; g < 4; ++g)
    k_split<<<256, 256, 0, stream>>>(wx[g], WxHi + (size_t)g * HID * EMB,
                                     WxLo + (size_t)g * HID * EMB, HID * EMB);
  k_split<<<512, 256, 0, stream>>>(Waa, WaaHi, WaaLo, HID * HID);
  k_bias2<<<8, 256, 0, stream>>>(bfp, bip, bop, bap, bias2);

  const int nch = SEQL / C;
  for (int ch = 0; ch < nch; ++ch) {
    int t0 = ch * C;
    dim3 gg(NTOT / 128, C * 2);
    k_gemm<<<gg, 256, 0, stream>>>(X + (size_t)t0 * BATCH * EMB, WxHi, WxLo,
                                   bias2, G2);
    k_rnn2<<<16, 1024, 0, stream>>>(WaaHi, WaaLo, G2, hSave, cSave, out, t0, C);
  }
}